// Round 1
// baseline (653.185 us; speedup 1.0000x reference)
//
#include <hip/hip_runtime.h>

// Problem constants (fixed by reference setup_inputs)
#define B_ 4
#define N_ 32768       // points per batch
#define C_ 128         // channels
#define D_ 32          // cubic dim
#define V_ (D_ * D_ * D_)   // 32768 voxels

// ---------------------------------------------------------------------------
// Kernel 1: transpose (B, C, V) -> (B, V, C) so the gather reads are
// contiguous in the channel dimension. Standard LDS-tiled transpose,
// tile 32x32, pad to 33 to kill bank conflicts.
// ---------------------------------------------------------------------------
__global__ __launch_bounds__(256) void transpose_kernel(
    const float* __restrict__ in,   // (B, C, V)
    float* __restrict__ out)        // (B, V, C)
{
    __shared__ float tile[32][33];
    const int b  = blockIdx.z;
    const int v0 = blockIdx.x * 32;
    const int c0 = blockIdx.y * 32;
    const float* inb  = in  + (size_t)b * C_ * V_;
    float*       outb = out + (size_t)b * C_ * V_;
    const int tx = threadIdx.x;   // 0..31  (fast: along V on read, along C on write)
    const int ty = threadIdx.y;   // 0..7

#pragma unroll
    for (int i = 0; i < 32; i += 8)
        tile[ty + i][tx] = inb[(size_t)(c0 + ty + i) * V_ + (v0 + tx)];

    __syncthreads();

#pragma unroll
    for (int i = 0; i < 32; i += 8)
        outb[(size_t)(v0 + ty + i) * C_ + (c0 + tx)] = tile[tx][ty + i];
}

// ---------------------------------------------------------------------------
// Kernel 2: gather from the transposed features.
// One 256-thread block per point. Thread t: corner k = t>>5, channel quad
// c4 = (t&31)*4. One float4 load (coalesced: 512 B contiguous per corner,
// dz-pairs give contiguous 1 KB) + one float4 store into the point's
// contiguous 4 KB output region.
// ---------------------------------------------------------------------------
__global__ __launch_bounds__(256) void gather_kernel(
    const float* __restrict__ ptcloud,   // (B, N, 3)
    const float* __restrict__ featsT,    // (B, V, C)
    float* __restrict__ out)             // (B, N, 8, C)
{
    const int point = blockIdx.x;        // 0 .. B_*N_-1
    const int b = point >> 15;           // N_ = 32768
    const int t = threadIdx.x;
    const int k  = t >> 5;               // corner 0..7
    const int c4 = (t & 31) << 2;        // channel quad base

    const float* pp = ptcloud + (size_t)point * 3;
    const float s = (D_ - 1) * 0.5f;     // 15.5
    const float fx = (pp[0] + 1.0f) * s;
    const float fy = (pp[1] + 1.0f) * s;
    const float fz = (pp[2] + 1.0f) * s;
    const int lx = (int)floorf(fx);
    const int ly = (int)floorf(fy);
    const int lz = (int)floorf(fz);

    const int ix = lx + (k >> 2);
    const int iy = ly + ((k >> 1) & 1);
    const int iz = lz + (k & 1);
    const bool valid = ((unsigned)ix < (unsigned)D_) &
                       ((unsigned)iy < (unsigned)D_) &
                       ((unsigned)iz < (unsigned)D_);
    const int cx = min(max(ix, 0), D_ - 1);
    const int cy = min(max(iy, 0), D_ - 1);
    const int cz = min(max(iz, 0), D_ - 1);
    const int flat = (cx * D_ + cy) * D_ + cz;

    const float4 v =
        *(const float4*)(featsT + ((size_t)b * V_ + flat) * C_ + c4);
    const float m = valid ? 1.0f : 0.0f;
    float4 r;
    r.x = v.x * m; r.y = v.y * m; r.z = v.z * m; r.w = v.w * m;

    *(float4*)(out + (((size_t)point * 8 + k) * C_) + c4) = r;
}

// ---------------------------------------------------------------------------
// Fallback: direct gather from (B, C, V) layout if workspace is too small
// for the transposed copy. Thread = channel; write coalesced, reads strided.
// ---------------------------------------------------------------------------
__global__ __launch_bounds__(128) void gather_direct_kernel(
    const float* __restrict__ ptcloud,   // (B, N, 3)
    const float* __restrict__ feats,     // (B, C, V)
    float* __restrict__ out)             // (B, N, 8, C)
{
    const int point = blockIdx.x;
    const int b = point >> 15;
    const int c = threadIdx.x;           // 0..127

    const float* pp = ptcloud + (size_t)point * 3;
    const float s = (D_ - 1) * 0.5f;
    const int lx = (int)floorf((pp[0] + 1.0f) * s);
    const int ly = (int)floorf((pp[1] + 1.0f) * s);
    const int lz = (int)floorf((pp[2] + 1.0f) * s);

    const float* fb = feats + ((size_t)b * C_ + c) * V_;
    float* ob = out + (size_t)point * 8 * C_ + c;

#pragma unroll
    for (int k = 0; k < 8; ++k) {
        const int ix = lx + (k >> 2);
        const int iy = ly + ((k >> 1) & 1);
        const int iz = lz + (k & 1);
        const bool valid = ((unsigned)ix < (unsigned)D_) &
                           ((unsigned)iy < (unsigned)D_) &
                           ((unsigned)iz < (unsigned)D_);
        const int cx = min(max(ix, 0), D_ - 1);
        const int cy = min(max(iy, 0), D_ - 1);
        const int cz = min(max(iz, 0), D_ - 1);
        const int flat = (cx * D_ + cy) * D_ + cz;
        ob[(size_t)k * C_] = fb[flat] * (valid ? 1.0f : 0.0f);
    }
}

extern "C" void kernel_launch(void* const* d_in, const int* in_sizes, int n_in,
                              void* d_out, int out_size, void* d_ws, size_t ws_size,
                              hipStream_t stream) {
    const float* ptcloud = (const float*)d_in[0];   // (B,N,3)
    const float* feats   = (const float*)d_in[1];   // (B,C,D,D,D)
    float* out = (float*)d_out;                     // (B,N,8,C)

    const size_t need = (size_t)B_ * C_ * V_ * sizeof(float);  // 64 MiB
    if (ws_size >= need) {
        float* featsT = (float*)d_ws;               // (B,V,C)
        dim3 tb(32, 8);
        dim3 tg(V_ / 32, C_ / 32, B_);              // (1024, 4, 4)
        transpose_kernel<<<tg, tb, 0, stream>>>(feats, featsT);
        gather_kernel<<<B_ * N_, 256, 0, stream>>>(ptcloud, featsT, out);
    } else {
        gather_direct_kernel<<<B_ * N_, 128, 0, stream>>>(ptcloud, feats, out);
    }
}